// Round 1
// 67.191 us; speedup vs baseline: 1.0543x; 1.0543x over previous
//
#include <hip/hip_runtime.h>
#include <math.h>

#define NCLS 10

// Closed-form "Pauli backprop" formulation.
//
// Circuit per patch: RY(alpha_w) [alpha = pixel + vp0_w] -> RZ(phi_w) ->
// CNOT(0,1)(1,2)(2,3) -> RY(theta_w) -> [RZ + CNOTs: folded] -> <Z_w>.
// Backprop observables through final CNOT chain: O_w = prod_{v<=w} Z_v.
// Through RY(theta): Z -> c1 Z - s1 X.  Through layer-0 CNOT chain each
// Pauli string maps to +/- a Pauli string.  Expectation on the encoding
// product state: <Z_w>=cos(alpha_w), <X_w>=sin(alpha_w)cos(phi_w),
// <Y_w>=sin(alpha_w)sin(phi_w).  phi/theta are uniform, so each e_w is a
// sum of (uniform coeff K) x (monomial in cA_w=cos alpha_w, sA_w=sin alpha_w):
//   e0 = K0*cA0 + K1*sA0sA1                                     (2 terms)
//   e1 = 4 terms, e2 = 8 terms, e3 = 16 terms  (30 total, derived below)

__global__ __launch_bounds__(256)
void quanv_fused(const float* __restrict__ x, const float* __restrict__ vp,
                 const float* __restrict__ W, const float* __restrict__ bias,
                 float* __restrict__ out) {
    __shared__ float K[30];
    __shared__ float4 feats4[196];
    __shared__ float logitsS[NCLS];

    const int b = blockIdx.x;
    const int t = threadIdx.x;

    // ---- uniform Pauli-term coefficients on one idle lane (t>=196 region) ----
    if (t == 224) {
        float c1[4], s1[4], fx[4], fy[4];
        #pragma unroll
        for (int w = 0; w < 4; ++w) {
            __sincosf(vp[8 + w], &s1[w], &c1[w]);  // layer-1 RY, FULL angle
            __sincosf(vp[4 + w], &fy[w], &fx[w]);  // layer-0 RZ, FULL angle
        }
        // e0:  Z0 -> { c0 * Z0 ; -s0 * X0X1 }
        K[0] = c1[0];
        K[1] = -s1[0] * fx[0] * fx[1];
        // e1 (Z0Z1):
        K[2] =  c1[0] * c1[1];                       // * cA1
        K[3] = -c1[0] * s1[1] * fx[1] * fx[2];       // * cA0 sA1 sA2
        K[4] =  s1[0] * c1[1] * fy[0] * fy[1];       // * sA0 sA1
        K[5] =  s1[0] * s1[1] * fx[0] * fx[2];       // * sA0 sA2
        // e2 (Z0Z1Z2):
        K[6]  =  c1[0] * c1[1] * c1[2];                            // cA0 cA2
        K[7]  = -c1[0] * c1[1] * s1[2] * fx[2] * fx[3];            // cA1 sA2 sA3
        K[8]  =  c1[0] * s1[1] * c1[2] * fy[1] * fy[2];            // sA1 sA2
        K[9]  =  c1[0] * s1[1] * s1[2] * fx[1] * fx[3];            // cA0 sA1 sA3
        K[10] = -s1[0] * c1[1] * c1[2] * fx[0] * fx[1];            // sA0 sA1 cA2
        K[11] = -s1[0] * c1[1] * s1[2] * fy[0] * fy[1] * fx[2] * fx[3]; // sA0 sA1 sA2 sA3
        K[12] = -s1[0] * s1[1] * c1[2] * fy[0] * fy[2];            // sA0 cA1 sA2
        K[13] = -s1[0] * s1[1] * s1[2] * fx[0] * fx[3];            // sA0 sA3
        // e3 (Z0Z1Z2Z3):
        K[14] =  c1[0] * c1[1] * c1[2] * c1[3];                    // cA1 cA3
        K[15] = -c1[0] * c1[1] * c1[2] * s1[3] * fx[3];            // cA0 cA2 sA3
        K[16] =  c1[0] * c1[1] * s1[2] * c1[3] * fy[2] * fy[3];    // cA0 sA2 sA3
        K[17] =  c1[0] * c1[1] * s1[2] * s1[3] * fx[2];            // cA1 sA2
        K[18] = -c1[0] * s1[1] * c1[2] * c1[3] * fx[1] * fx[2];    // cA0 sA1 sA2 cA3
        K[19] = -c1[0] * s1[1] * c1[2] * s1[3] * fy[1] * fy[2] * fx[3]; // sA1 sA2 sA3
        K[20] = -c1[0] * s1[1] * s1[2] * c1[3] * fy[1] * fy[3];    // sA1 cA2 sA3
        K[21] = -c1[0] * s1[1] * s1[2] * s1[3] * fx[1];            // cA0 sA1
        K[22] =  s1[0] * c1[1] * c1[2] * c1[3] * fy[0] * fy[1];    // sA0 sA1 cA3
        K[23] =  s1[0] * c1[1] * c1[2] * s1[3] * fx[0] * fx[1] * fx[3]; // sA0 sA1 cA2 sA3
        K[24] = -s1[0] * c1[1] * s1[2] * c1[3] * fx[0] * fx[1] * fy[2] * fy[3]; // sA0 sA1 sA2 sA3
        K[25] =  s1[0] * c1[1] * s1[2] * s1[3] * fy[0] * fy[1] * fx[2]; // sA0 sA1 sA2
        K[26] =  s1[0] * s1[1] * c1[2] * c1[3] * fx[0] * fx[2];    // sA0 sA2 cA3
        K[27] =  s1[0] * s1[1] * c1[2] * s1[3] * fy[0] * fy[2] * fx[3]; // sA0 cA1 sA2 sA3
        K[28] =  s1[0] * s1[1] * s1[2] * c1[3] * fy[0] * fy[3];    // sA0 cA1 cA2 sA3
        K[29] =  s1[0] * s1[1] * s1[2] * s1[3] * fx[0];            // sA0
    }

    const bool is_sim = (t < 196);
    float cA[4], sA[4];
    if (is_sim) {
        const int i = t / 14;
        const int j = t - i * 14;
        const float* xb = x + b * 784 + 2 * i * 28 + 2 * j;
        const float2 A  = *(const float2*)xb;
        const float2 Bv = *(const float2*)(xb + 28);
        // FULL angle alpha = pixel + layer-0 RY param (not half-angle).
        __sincosf(A.x  + vp[0], &sA[0], &cA[0]);
        __sincosf(A.y  + vp[1], &sA[1], &cA[1]);
        __sincosf(Bv.x + vp[2], &sA[2], &cA[2]);
        __sincosf(Bv.y + vp[3], &sA[3], &cA[3]);
    }
    __syncthreads();   // publish K

    if (is_sim) {
        const float s01 = sA[0] * sA[1];
        const float s23 = sA[2] * sA[3];
        const float e0 = K[0] * cA[0] + K[1] * s01;
        const float e1 = K[2] * cA[1] + K[3] * (cA[0] * sA[1] * sA[2])
                       + K[4] * s01   + K[5] * (sA[0] * sA[2]);
        const float e2 = K[6]  * (cA[0] * cA[2])
                       + K[7]  * (cA[1] * s23)
                       + K[8]  * (sA[1] * sA[2])
                       + K[9]  * (cA[0] * sA[1] * sA[3])
                       + K[10] * (s01 * cA[2])
                       + K[11] * (s01 * s23)
                       + K[12] * (sA[0] * cA[1] * sA[2])
                       + K[13] * (sA[0] * sA[3]);
        const float e3 = K[14] * (cA[1] * cA[3])
                       + K[15] * (cA[0] * cA[2] * sA[3])
                       + K[16] * (cA[0] * s23)
                       + K[17] * (cA[1] * sA[2])
                       + K[18] * (cA[0] * sA[1] * sA[2] * cA[3])
                       + K[19] * (sA[1] * s23)
                       + K[20] * (sA[1] * cA[2] * sA[3])
                       + K[21] * (cA[0] * sA[1])
                       + K[22] * (s01 * cA[3])
                       + K[23] * (s01 * cA[2] * sA[3])
                       + K[24] * (s01 * s23)
                       + K[25] * (s01 * sA[2])
                       + K[26] * (sA[0] * sA[2] * cA[3])
                       + K[27] * (sA[0] * cA[1] * sA[2] * sA[3])
                       + K[28] * (sA[0] * cA[1] * cA[2] * sA[3])
                       + K[29] * sA[0];
        feats4[t] = make_float4(e0, e1, e2, e3);
    }
    __syncthreads();

    // ---- GEMV: thread (c = t>>4 in [0,10), j = t&15), strided float4 chunks ----
    const int c = t >> 4, j = t & 15;
    float acc = 0.0f;
    if (c < NCLS) {
        const float4* __restrict__ W4 = (const float4*)W;
        #pragma unroll
        for (int i2 = 0; i2 < 12; ++i2) {
            const int v = j + 16 * i2;
            const float4 f = feats4[v];
            const float4 w = W4[c * 196 + v];
            acc += f.x * w.x + f.y * w.y + f.z * w.z + f.w * w.w;
        }
        if (j < 4) {
            const int v = j + 192;
            const float4 f = feats4[v];
            const float4 w = W4[c * 196 + v];
            acc += f.x * w.x + f.y * w.y + f.z * w.z + f.w * w.w;
        }
    }
    acc += __shfl_down(acc, 8, 16);
    acc += __shfl_down(acc, 4, 16);
    acc += __shfl_down(acc, 2, 16);
    acc += __shfl_down(acc, 1, 16);
    if (j == 0 && c < NCLS) logitsS[c] = acc + bias[c];
    __syncthreads();

    if (t < NCLS) {
        float m = -1e30f;
        #pragma unroll
        for (int k = 0; k < NCLS; ++k) m = fmaxf(m, logitsS[k]);
        float ssum = 0.0f;
        #pragma unroll
        for (int k = 0; k < NCLS; ++k) ssum += __expf(logitsS[k] - m);
        out[b * NCLS + t] = logitsS[t] - m - __logf(ssum);
    }
}

extern "C" void kernel_launch(void* const* d_in, const int* in_sizes, int n_in,
                              void* d_out, int out_size, void* d_ws, size_t ws_size,
                              hipStream_t stream) {
    const float* x  = (const float*)d_in[0];   // (2048, 28, 28)
    const float* vp = (const float*)d_in[1];   // (2, 2, 4)
    const float* W  = (const float*)d_in[2];   // (10, 784)
    const float* bb = (const float*)d_in[3];   // (10,)
    float* out = (float*)d_out;                // (2048, 10)

    quanv_fused<<<2048, 256, 0, stream>>>(x, vp, W, bb, out);
}